// Round 19
// baseline (125.547 us; speedup 1.0000x reference)
//
#include <hip/hip_runtime.h>
#include <hip/hip_bf16.h>

#define BATCH 8
#define SEQ 4096
#define EMB 1024
#define HEAD 64
#define N3 192      // 3*HEAD: k | q | v

#define BM 64       // qkv block rows
#define BK 64       // qkv K-step
#define NT (EMB / BK)
#define LSTR 72     // padded LDS row stride in ushorts (64 + 8): 144B = 9*16B

typedef __attribute__((ext_vector_type(4))) float f32x4;
typedef __attribute__((ext_vector_type(8))) short bf16x8;
typedef __attribute__((ext_vector_type(4))) short short4v;
typedef __attribute__((ext_vector_type(4))) float float4v;
typedef __attribute__((ext_vector_type(2))) unsigned int u32x2;

#define LOG2E 1.4426950408889634f
#define QSCALE (0.125f * LOG2E)   // 1/sqrt(64) folded with log2e: scores in log2 domain

// raw v_exp_f32 (exp2): 1 inst vs libm exp2f's ~5
#define FEXP2(x) __builtin_amdgcn_exp2f(x)
// pack two f32 to bf16 pair (truncating) in 1 inst: [b.hi16 | a.hi16]
#define BFPACK(a, b) __builtin_amdgcn_perm(__builtin_bit_cast(unsigned int, (b)), \
                                           __builtin_bit_cast(unsigned int, (a)), 0x07060302u)

static __device__ __forceinline__ unsigned short f2bf(float f) {
  unsigned int x = __builtin_bit_cast(unsigned int, f);
  x += 0x7fffu + ((x >> 16) & 1u);   // RTNE
  return (unsigned short)(x >> 16);
}

// --- Kernel 1: W [1024][192] f32 -> Wt [192][1024] bf16 ---
__global__ __launch_bounds__(256) void wt_kernel(const float* __restrict__ W,
                                                 unsigned short* __restrict__ Wt) {
  int idx = blockIdx.x * 256 + threadIdx.x;
  int k = idx / N3, c = idx % N3;
  Wt[(size_t)c * EMB + k] = f2bf(W[idx]);
}

// --- Kernel 2: canonical LDS-staged GEMM, epilogue packs fragment-linear ---
__global__ __launch_bounds__(256, 2) void qkv_kernel(const float* __restrict__ x,
                                                     const unsigned short* __restrict__ Wt,
                                                     unsigned short* __restrict__ PK,
                                                     unsigned short* __restrict__ PQ,
                                                     unsigned short* __restrict__ PV) {
  __shared__ unsigned short Asm[2][BM][LSTR];    // 2 x 64 x 144B = 18.4 KB
  __shared__ unsigned short Bsm[2][N3][LSTR];    // 2 x 192 x 144B = 55.3 KB

  const int tid = threadIdx.x;
  const int wid = tid >> 6;
  const int lane = tid & 63;
  const int l16 = lane & 15;
  const int lg = lane >> 4;
  const int m0 = blockIdx.x * BM;

  const int ar0 = tid >> 4;        // A row base: +16*i, i<4
  const int ac4 = tid & 15;        // A float4-chunk in row
  const int br0 = tid >> 3;        // B row base: +32*i, i<6
  const int bc = tid & 7;          // B bf16x8-chunk in row

  const float* xa = x + (size_t)(m0 + ar0) * EMB + ac4 * 4;
  const unsigned short* wb = Wt + (size_t)br0 * EMB + bc * 8;

  f32x4 acc[4][3];
#pragma unroll
  for (int mi = 0; mi < 4; ++mi)
#pragma unroll
    for (int ni = 0; ni < 3; ++ni) acc[mi][ni] = (f32x4)0.0f;

  float4v av[4];
  bf16x8 bv[6];

#define ISSUE_LOADS(K0)                                                        \
  {                                                                            \
    _Pragma("unroll") for (int i = 0; i < 4; ++i)                              \
        av[i] = *(const float4v*)(xa + (size_t)(16 * i) * EMB + (K0));         \
    _Pragma("unroll") for (int i = 0; i < 6; ++i)                              \
        bv[i] = *(const bf16x8*)(wb + (size_t)(32 * i) * EMB + (K0));          \
  }

#define WRITE_LDS(BUF)                                                         \
  {                                                                            \
    _Pragma("unroll") for (int i = 0; i < 4; ++i) {                            \
      short4v p;                                                               \
      _Pragma("unroll") for (int j = 0; j < 4; ++j)                            \
          p[j] = (short)f2bf(av[i][j]);                                        \
      *(short4v*)&Asm[BUF][ar0 + 16 * i][ac4 * 4] = p;                         \
    }                                                                          \
    _Pragma("unroll") for (int i = 0; i < 6; ++i)                              \
        *(bf16x8*)&Bsm[BUF][br0 + 32 * i][bc * 8] = bv[i];                     \
  }

#define COMPUTE(BUF)                                                           \
  {                                                                            \
    _Pragma("unroll") for (int kh = 0; kh < 2; ++kh) {                         \
      bf16x8 af[4], bfr[3];                                                    \
      _Pragma("unroll") for (int mi = 0; mi < 4; ++mi)                         \
          af[mi] = *(const bf16x8*)&Asm[BUF][mi * 16 + l16][kh * 32 + lg * 8]; \
      _Pragma("unroll") for (int ni = 0; ni < 3; ++ni)                         \
          bfr[ni] = *(const bf16x8*)&Bsm[BUF][wid * 48 + ni * 16 + l16][kh * 32 + lg * 8]; \
      _Pragma("unroll") for (int mi = 0; mi < 4; ++mi)                         \
        _Pragma("unroll") for (int ni = 0; ni < 3; ++ni)                       \
            acc[mi][ni] = __builtin_amdgcn_mfma_f32_16x16x32_bf16(             \
                af[mi], bfr[ni], acc[mi][ni], 0, 0, 0);                        \
    }                                                                          \
  }

  ISSUE_LOADS(0)
  WRITE_LDS(0)
  __syncthreads();

  int cur = 0;
  for (int t = 0; t < NT; ++t) {
    if (t < NT - 1) ISSUE_LOADS((t + 1) * BK)
    COMPUTE(cur)
    if (t < NT - 1) {
      WRITE_LDS(cur ^ 1)
    }
    __syncthreads();
    cur ^= 1;
  }
#undef ISSUE_LOADS
#undef WRITE_LDS
#undef COMPUTE

  // epilogue: D col = n (l16-resident), row = m0 + mi*16 + lg*4 + r
#pragma unroll
  for (int mi = 0; mi < 4; ++mi) {
#pragma unroll
    for (int ni = 0; ni < 3; ++ni) {
      const int n = wid * 48 + ni * 16 + l16;
#pragma unroll
      for (int r = 0; r < 4; ++r) {
        const int row = m0 + mi * 16 + lg * 4 + r;
        const int bb = row >> 12;
        const int ss = row & (SEQ - 1);
        const float v = acc[mi][ni][r];
        if (n < 64) {            // K
          PK[(((size_t)bb * 256 + (ss >> 4)) * 2 + (n >> 5)) * 512 +
             (ss & 15) * 32 + (n & 31)] = f2bf(v);
        } else if (n < 128) {    // Q (pre-scaled 1/sqrt(64) * log2e)
          const int d = n - 64;
          PQ[(((size_t)bb * 256 + (ss >> 4)) * 2 + (d >> 5)) * 512 +
             (ss & 15) * 32 + (d & 31)] = f2bf(v * QSCALE);
        } else {                 // V
          const int d = n - 128;
          PV[(((size_t)bb * 64 + (ss >> 6)) * 8 + (d >> 4) * 2 + ((ss >> 5) & 1)) * 512 +
             (d & 15) * 32 + (ss & 31)] = f2bf(v);
        }
      }
    }
  }
}

// --- Kernel 3: causal flash attention (r14 structure + V prefetch).
// 1024 blocks, 4 waves. Wave owns two 16-row q-chunks over its KV-split
// quarter. Running pointers, cross-iteration K AND V prefetch (both one tile
// ahead so every load has a full tile of latency cover), setprio, LDS
// P-transpose, FEXP2 softmax, BFPACK, online max, two-phase LSE merge.
__global__ __launch_bounds__(256, 3) void attn_kernel(const unsigned short* __restrict__ PK,
                                                      const unsigned short* __restrict__ PQ,
                                                      const unsigned short* __restrict__ PV,
                                                      float* __restrict__ out) {
  __shared__ float Msm[4][16];
  __shared__ float Lsm[4][16];
  __shared__ float Osm[4][4][16][17];            // [wave][dd][d-row][q] (+1 pad)
  __shared__ unsigned short Pl[4][2][16][LSTR];  // per-wave P^T double buffer [q][kv]

  const int tid = threadIdx.x;
  const int wid = tid >> 6;
  const int lane = tid & 63;
  const int l16 = lane & 15;
  const int lg = lane >> 4;
  const int lam = (l16 * 4 + lg) * 8;   // lane's ushort offset in a 1KB sub-tile

  const int Bid = blockIdx.x;
  const int b = Bid & 7;                     // batch (XCD affinity)
  const int i_ = (Bid >> 3) & 31;
  const int j_ = Bid >> 8;
  const int p = (j_ == 0) ? i_ : (j_ == 1) ? (127 - i_) : (j_ == 2) ? (32 + i_) : (95 - i_);
  const int qc0 = 2 * p, qc1 = 2 * p + 1;
  const int q0a = qc0 * 16, q0b = qc1 * 16;
  const int T_total = (q0b + 16 + 63) >> 6;  // tiles covering KV [0, q0b+16)
  const int t0 = (wid * T_total) >> 2;
  const int t1 = ((wid + 1) * T_total) >> 2;

  const unsigned short* pqb = PQ + (size_t)b * 256 * 1024;

  // Q fragments for both chunks (B-operand of S^T mfma)
  bf16x8 qa0 = *(const bf16x8*)(pqb + ((size_t)qc0 * 2 + 0) * 512 + lam);
  bf16x8 qa1 = *(const bf16x8*)(pqb + ((size_t)qc0 * 2 + 1) * 512 + lam);
  bf16x8 qb0 = *(const bf16x8*)(pqb + ((size_t)qc1 * 2 + 0) * 512 + lam);
  bf16x8 qb1 = *(const bf16x8*)(pqb + ((size_t)qc1 * 2 + 1) * 512 + lam);

  f32x4 oA[4], oB[4];
#pragma unroll
  for (int dd = 0; dd < 4; ++dd) { oA[dd] = (f32x4)0.0f; oB[dd] = (f32x4)0.0f; }
  float mA = -3.0e38f, lA = 0.0f, mB = -3.0e38f, lB = 0.0f;

  // running pointers (strength-reduced): K tile = 4096 ushorts, V tile = 4096
  const unsigned short* kp = PK + (size_t)b * 256 * 1024 + (size_t)t0 * 4096 + lam;
  const unsigned short* vp = PV + (size_t)b * 64 * 8 * 512 + (size_t)t0 * 4096 + lam;

  if (t0 < t1) {
    // preload K and V tile t0
    bf16x8 kf[8], kn[8], vf[8], vn[8];
#pragma unroll
    for (int t = 0; t < 4; ++t) {
      kf[2 * t] = *(const bf16x8*)(kp + t * 1024);
      kf[2 * t + 1] = *(const bf16x8*)(kp + t * 1024 + 512);
      vf[2 * t] = *(const bf16x8*)(vp + t * 1024);
      vf[2 * t + 1] = *(const bf16x8*)(vp + t * 1024 + 512);
    }

    for (int it = t0; it < t1; ++it) {
      const int kv0 = it << 6;

      // prefetch next K and V tiles (unconditional; last reads land in the
      // adjacent ws region, never consumed)
#pragma unroll
      for (int t = 0; t < 4; ++t) {
        kn[2 * t] = *(const bf16x8*)(kp + 4096 + t * 1024);
        kn[2 * t + 1] = *(const bf16x8*)(kp + 4096 + t * 1024 + 512);
        vn[2 * t] = *(const bf16x8*)(vp + 4096 + t * 1024);
        vn[2 * t + 1] = *(const bf16x8*)(vp + 4096 + t * 1024 + 512);
      }

      // QK^T for both chunks from kf
      f32x4 s0[4], s1[4];
      __builtin_amdgcn_s_setprio(1);
#pragma unroll
      for (int t = 0; t < 4; ++t) {
        f32x4 z = (f32x4)0.0f;
        z = __builtin_amdgcn_mfma_f32_16x16x32_bf16(kf[2 * t], qa0, z, 0, 0, 0);
        s0[t] = __builtin_amdgcn_mfma_f32_16x16x32_bf16(kf[2 * t + 1], qa1, z, 0, 0, 0);
        z = (f32x4)0.0f;
        z = __builtin_amdgcn_mfma_f32_16x16x32_bf16(kf[2 * t], qb0, z, 0, 0, 0);
        s1[t] = __builtin_amdgcn_mfma_f32_16x16x32_bf16(kf[2 * t + 1], qb1, z, 0, 0, 0);
      }
      __builtin_amdgcn_s_setprio(0);

      // ---- chunk A: mask, softmax (log2 domain), P->LDS, PV ----
      if (kv0 + 64 > q0a) {
        const int base = kv0 + lg * 4 - q0a - l16;
#pragma unroll
        for (int t = 0; t < 4; ++t)
#pragma unroll
          for (int r = 0; r < 4; ++r)
            if (base + 16 * t + r > 0) s0[t][r] = -3.0e38f;
      }
      {
        float mx = s0[0][0];
#pragma unroll
        for (int t = 0; t < 4; ++t)
#pragma unroll
          for (int r = 0; r < 4; ++r) mx = fmaxf(mx, s0[t][r]);
        mx = fmaxf(mx, __shfl_xor(mx, 16));
        mx = fmaxf(mx, __shfl_xor(mx, 32));
        if (!__all(mx <= mA)) {
          float mn = fmaxf(mA, mx);
          float al = FEXP2(mA - mn);
          mA = mn; lA *= al;
#pragma unroll
          for (int dd = 0; dd < 4; ++dd) oA[dd] *= al;
        }
        float ps = 0.0f;
#pragma unroll
        for (int t = 0; t < 4; ++t) {
          float p0 = FEXP2(s0[t][0] - mA);
          float p1 = FEXP2(s0[t][1] - mA);
          float p2 = FEXP2(s0[t][2] - mA);
          float p3 = FEXP2(s0[t][3] - mA);
          ps += (p0 + p1) + (p2 + p3);
          u32x2 w;
          w[0] = BFPACK(p0, p1);
          w[1] = BFPACK(p2, p3);
          *(u32x2*)&Pl[wid][0][l16][16 * t + lg * 4] = w;   // P^T[q=l16][kv]
        }
        ps += __shfl_xor(ps, 16);
        ps += __shfl_xor(ps, 32);
        lA += ps;
      }
      {
        bf16x8 pf0 = *(const bf16x8*)&Pl[wid][0][l16][lg * 8];
        bf16x8 pf1 = *(const bf16x8*)&Pl[wid][0][l16][32 + lg * 8];
        __builtin_amdgcn_s_setprio(1);
#pragma unroll
        for (int dd = 0; dd < 4; ++dd) {
          oA[dd] = __builtin_amdgcn_mfma_f32_16x16x32_bf16(vf[2 * dd], pf0, oA[dd], 0, 0, 0);
          oA[dd] = __builtin_amdgcn_mfma_f32_16x16x32_bf16(vf[2 * dd + 1], pf1, oA[dd], 0, 0, 0);
        }
        __builtin_amdgcn_s_setprio(0);
      }

      // ---- chunk B ----
      if (kv0 + 64 > q0b) {
        const int base = kv0 + lg * 4 - q0b - l16;
#pragma unroll
        for (int t = 0; t < 4; ++t)
#pragma unroll
          for (int r = 0; r < 4; ++r)
            if (base + 16 * t + r > 0) s1[t][r] = -3.0e38f;
      }
      {
        float mx = s1[0][0];
#pragma unroll
        for (int t = 0; t < 4; ++t)
#pragma unroll
          for (int r = 0; r < 4; ++r) mx = fmaxf(mx, s1[t][r]);
        mx = fmaxf(mx, __shfl_xor(mx, 16));
        mx = fmaxf(mx, __shfl_xor(mx, 32));
        if (!__all(mx <= mB)) {
          float mn = fmaxf(mB, mx);
          float al = FEXP2(mB - mn);
          mB = mn; lB *= al;
#pragma unroll
          for (int dd = 0; dd < 4; ++dd) oB[dd] *= al;
        }
        float ps = 0.0f;
#pragma unroll
        for (int t = 0; t < 4; ++t) {
          float p0 = FEXP2(s1[t][0] - mB);
          float p1 = FEXP2(s1[t][1] - mB);
          float p2 = FEXP2(s1[t][2] - mB);
          float p3 = FEXP2(s1[t][3] - mB);
          ps += (p0 + p1) + (p2 + p3);
          u32x2 w;
          w[0] = BFPACK(p0, p1);
          w[1] = BFPACK(p2, p3);
          *(u32x2*)&Pl[wid][1][l16][16 * t + lg * 4] = w;
        }
        ps += __shfl_xor(ps, 16);
        ps += __shfl_xor(ps, 32);
        lB += ps;
      }
      {
        bf16x8 pf0 = *(const bf16x8*)&Pl[wid][1][l16][lg * 8];
        bf16x8 pf1 = *(const bf16x8*)&Pl[wid][1][l16][32 + lg * 8];
        __builtin_amdgcn_s_setprio(1);
#pragma unroll
        for (int dd = 0; dd < 4; ++dd) {
          oB[dd] = __builtin_amdgcn_mfma_f32_16x16x32_bf16(vf[2 * dd], pf0, oB[dd], 0, 0, 0);
          oB[dd] = __builtin_amdgcn_mfma_f32_16x16x32_bf16(vf[2 * dd + 1], pf1, oB[dd], 0, 0, 0);
        }
        __builtin_amdgcn_s_setprio(0);
      }

#pragma unroll
      for (int j = 0; j < 8; ++j) { kf[j] = kn[j]; vf[j] = vn[j]; }
      kp += 4096;
      vp += 4096;
    }
  }

  // ---- two-phase LSE merge (reuse LDS) ----
#define MERGE_PHASE(MV, LV, OV, Q0)                                            \
  {                                                                            \
    if (lg == 0) { Msm[wid][l16] = MV; Lsm[wid][l16] = LV; }                   \
    _Pragma("unroll") for (int dd = 0; dd < 4; ++dd)                           \
      _Pragma("unroll") for (int r = 0; r < 4; ++r)                            \
          Osm[wid][dd][lg * 4 + r][l16] = OV[dd][r];                           \
    __syncthreads();                                                           \
    if (wid == 0) {                                                            \
      float M = Msm[0][l16];                                                   \
      _Pragma("unroll") for (int w = 1; w < 4; ++w) M = fmaxf(M, Msm[w][l16]); \
      float L = 0.0f;                                                          \
      f32x4 oc[4];                                                             \
      _Pragma("unroll") for (int dd = 0; dd < 4; ++dd) oc[dd] = (f32x4)0.0f;   \
      _Pragma("unroll") for (int w = 0; w < 4; ++w) {                          \
        float sc = FEXP2(Msm[w][l16] - M);                                     \
        L += Lsm[w][l16] * sc;                                                 \
        _Pragma("unroll") for (int dd = 0; dd < 4; ++dd)                       \
          _Pragma("unroll") for (int r = 0; r < 4; ++r)                        \
              oc[dd][r] += Osm[w][dd][lg * 4 + r][l16] * sc;                   \
      }                                                                        \
      const float inv = 1.0f / L;                                              \
      float* op = out + ((size_t)b * SEQ + (Q0) + l16) * HEAD;                 \
      _Pragma("unroll") for (int dd = 0; dd < 4; ++dd)                         \
        _Pragma("unroll") for (int r = 0; r < 4; ++r)                          \
            op[16 * dd + lg * 4 + r] = oc[dd][r] * inv;                        \
    }                                                                          \
    __syncthreads();                                                           \
  }
  MERGE_PHASE(mA, lA, oA, q0a)
  MERGE_PHASE(mB, lB, oB, q0b)
#undef MERGE_PHASE
}

extern "C" void kernel_launch(void* const* d_in, const int* in_sizes, int n_in,
                              void* d_out, int out_size, void* d_ws, size_t ws_size,
                              hipStream_t stream) {
  (void)in_sizes; (void)n_in; (void)out_size; (void)ws_size;
  const float* x = (const float*)d_in[0];
  const float* W = (const float*)d_in[1];
  float* out = (float*)d_out;

  const size_t MB4 = (size_t)4 * 1024 * 1024;
  unsigned short* Wt = (unsigned short*)d_ws;                               // 384 KB
  unsigned short* PK = (unsigned short*)((char*)d_ws + 512 * 1024);         // 4 MB
  unsigned short* PQ = (unsigned short*)((char*)d_ws + 512 * 1024 + MB4);   // 4 MB
  unsigned short* PV = (unsigned short*)((char*)d_ws + 512 * 1024 + 2 * MB4); // 4 MB

  hipLaunchKernelGGL(wt_kernel, dim3((EMB * N3) / 256), dim3(256), 0, stream, W, Wt);
  hipLaunchKernelGGL(qkv_kernel, dim3((BATCH * SEQ) / BM), dim3(256), 0, stream, x, Wt, PK, PQ, PV);
  hipLaunchKernelGGL(attn_kernel, dim3(BATCH * 128), dim3(256), 0, stream, PK, PQ, PV, out);
}

// Round 20
// 83.400 us; speedup vs baseline: 1.5054x; 1.5054x over previous
//
#include <hip/hip_runtime.h>
#include <hip/hip_bf16.h>

#define BATCH 8
#define SEQ 4096
#define EMB 1024
#define HEAD 64
#define N3 192      // 3*HEAD: k | q | v

#define BM 64       // qkv block rows
#define BK 64       // qkv K-step
#define NT (EMB / BK)
#define LSTR 72     // padded LDS row stride in ushorts (64 + 8): 144B = 9*16B

typedef __attribute__((ext_vector_type(4))) float f32x4;
typedef __attribute__((ext_vector_type(8))) short bf16x8;
typedef __attribute__((ext_vector_type(4))) short short4v;
typedef __attribute__((ext_vector_type(4))) float float4v;
typedef __attribute__((ext_vector_type(2))) unsigned int u32x2;

#define LOG2E 1.4426950408889634f
#define QSCALE (0.125f * LOG2E)   // 1/sqrt(64) folded with log2e: scores in log2 domain

// raw v_exp_f32 (exp2): 1 inst vs libm exp2f's ~5 (arg <= 0 here; -3e38 -> 0)
#define FEXP2(x) __builtin_amdgcn_exp2f(x)
// pack two f32 to bf16 pair (truncating) in 1 inst: [b.hi16 | a.hi16]
#define BFPACK(a, b) __builtin_amdgcn_perm(__builtin_bit_cast(unsigned int, (b)), \
                                           __builtin_bit_cast(unsigned int, (a)), 0x07060302u)

static __device__ __forceinline__ unsigned short f2bf(float f) {
  unsigned int x = __builtin_bit_cast(unsigned int, f);
  x += 0x7fffu + ((x >> 16) & 1u);   // RTNE
  return (unsigned short)(x >> 16);
}

// --- Kernel 1: W [1024][192] f32 -> Wt [192][1024] bf16 ---
__global__ __launch_bounds__(256) void wt_kernel(const float* __restrict__ W,
                                                 unsigned short* __restrict__ Wt) {
  int idx = blockIdx.x * 256 + threadIdx.x;
  int k = idx / N3, c = idx % N3;
  Wt[(size_t)c * EMB + k] = f2bf(W[idx]);
}

// --- Kernel 2: canonical LDS-staged GEMM, epilogue packs fragment-linear ---
__global__ __launch_bounds__(256, 2) void qkv_kernel(const float* __restrict__ x,
                                                     const unsigned short* __restrict__ Wt,
                                                     unsigned short* __restrict__ PK,
                                                     unsigned short* __restrict__ PQ,
                                                     unsigned short* __restrict__ PV) {
  __shared__ unsigned short Asm[2][BM][LSTR];    // 2 x 64 x 144B = 18.4 KB
  __shared__ unsigned short Bsm[2][N3][LSTR];    // 2 x 192 x 144B = 55.3 KB

  const int tid = threadIdx.x;
  const int wid = tid >> 6;
  const int lane = tid & 63;
  const int l16 = lane & 15;
  const int lg = lane >> 4;
  const int m0 = blockIdx.x * BM;

  const int ar0 = tid >> 4;        // A row base: +16*i, i<4
  const int ac4 = tid & 15;        // A float4-chunk in row
  const int br0 = tid >> 3;        // B row base: +32*i, i<6
  const int bc = tid & 7;          // B bf16x8-chunk in row

  const float* xa = x + (size_t)(m0 + ar0) * EMB + ac4 * 4;
  const unsigned short* wb = Wt + (size_t)br0 * EMB + bc * 8;

  f32x4 acc[4][3];
#pragma unroll
  for (int mi = 0; mi < 4; ++mi)
#pragma unroll
    for (int ni = 0; ni < 3; ++ni) acc[mi][ni] = (f32x4)0.0f;

  float4v av[4];
  bf16x8 bv[6];

#define ISSUE_LOADS(K0)                                                        \
  {                                                                            \
    _Pragma("unroll") for (int i = 0; i < 4; ++i)                              \
        av[i] = *(const float4v*)(xa + (size_t)(16 * i) * EMB + (K0));         \
    _Pragma("unroll") for (int i = 0; i < 6; ++i)                              \
        bv[i] = *(const bf16x8*)(wb + (size_t)(32 * i) * EMB + (K0));          \
  }

#define WRITE_LDS(BUF)                                                         \
  {                                                                            \
    _Pragma("unroll") for (int i = 0; i < 4; ++i) {                            \
      short4v p;                                                               \
      _Pragma("unroll") for (int j = 0; j < 4; ++j)                            \
          p[j] = (short)f2bf(av[i][j]);                                        \
      *(short4v*)&Asm[BUF][ar0 + 16 * i][ac4 * 4] = p;                         \
    }                                                                          \
    _Pragma("unroll") for (int i = 0; i < 6; ++i)                              \
        *(bf16x8*)&Bsm[BUF][br0 + 32 * i][bc * 8] = bv[i];                     \
  }

#define COMPUTE(BUF)                                                           \
  {                                                                            \
    _Pragma("unroll") for (int kh = 0; kh < 2; ++kh) {                         \
      bf16x8 af[4], bfr[3];                                                    \
      _Pragma("unroll") for (int mi = 0; mi < 4; ++mi)                         \
          af[mi] = *(const bf16x8*)&Asm[BUF][mi * 16 + l16][kh * 32 + lg * 8]; \
      _Pragma("unroll") for (int ni = 0; ni < 3; ++ni)                         \
          bfr[ni] = *(const bf16x8*)&Bsm[BUF][wid * 48 + ni * 16 + l16][kh * 32 + lg * 8]; \
      _Pragma("unroll") for (int mi = 0; mi < 4; ++mi)                         \
        _Pragma("unroll") for (int ni = 0; ni < 3; ++ni)                       \
            acc[mi][ni] = __builtin_amdgcn_mfma_f32_16x16x32_bf16(             \
                af[mi], bfr[ni], acc[mi][ni], 0, 0, 0);                        \
    }                                                                          \
  }

  ISSUE_LOADS(0)
  WRITE_LDS(0)
  __syncthreads();

  int cur = 0;
  for (int t = 0; t < NT; ++t) {
    if (t < NT - 1) ISSUE_LOADS((t + 1) * BK)
    COMPUTE(cur)
    if (t < NT - 1) {
      WRITE_LDS(cur ^ 1)
    }
    __syncthreads();
    cur ^= 1;
  }
#undef ISSUE_LOADS
#undef WRITE_LDS
#undef COMPUTE

  // epilogue: D col = n (l16-resident), row = m0 + mi*16 + lg*4 + r
#pragma unroll
  for (int mi = 0; mi < 4; ++mi) {
#pragma unroll
    for (int ni = 0; ni < 3; ++ni) {
      const int n = wid * 48 + ni * 16 + l16;
#pragma unroll
      for (int r = 0; r < 4; ++r) {
        const int row = m0 + mi * 16 + lg * 4 + r;
        const int bb = row >> 12;
        const int ss = row & (SEQ - 1);
        const float v = acc[mi][ni][r];
        if (n < 64) {            // K
          PK[(((size_t)bb * 256 + (ss >> 4)) * 2 + (n >> 5)) * 512 +
             (ss & 15) * 32 + (n & 31)] = f2bf(v);
        } else if (n < 128) {    // Q (pre-scaled 1/sqrt(64) * log2e)
          const int d = n - 64;
          PQ[(((size_t)bb * 256 + (ss >> 4)) * 2 + (d >> 5)) * 512 +
             (ss & 15) * 32 + (d & 31)] = f2bf(v * QSCALE);
        } else {                 // V
          const int d = n - 128;
          PV[(((size_t)bb * 64 + (ss >> 6)) * 8 + (d >> 4) * 2 + ((ss >> 5) & 1)) * 512 +
             (d & 15) * 32 + (ss & 31)] = f2bf(v);
        }
      }
    }
  }
}

// --- Kernel 3: causal flash attention (r12 structure). 1024 blocks, 4 waves.
// Wave owns two 16-row q-chunks over its KV-split quarter. Running pointers,
// cross-iteration K prefetch, setprio, LDS P-transpose, raw v_exp_f32 softmax,
// v_perm bf16 pack. Best measured configuration (83.6 us total).
// NOTE: do NOT add V-prefetch (r19) / pair-wider (r10) / (512,4) (r17):
// all spill past the ~84-VGPR allocation and regress 15-50%.
__global__ __launch_bounds__(256, 3) void attn_kernel(const unsigned short* __restrict__ PK,
                                                      const unsigned short* __restrict__ PQ,
                                                      const unsigned short* __restrict__ PV,
                                                      float* __restrict__ out) {
  __shared__ float Msm[4][16];
  __shared__ float Lsm[4][16];
  __shared__ float Osm[4][4][16][17];            // [wave][dd][d-row][q] (+1 pad)
  __shared__ unsigned short Pl[4][2][16][LSTR];  // per-wave P^T double buffer [q][kv]

  const int tid = threadIdx.x;
  const int wid = tid >> 6;
  const int lane = tid & 63;
  const int l16 = lane & 15;
  const int lg = lane >> 4;
  const int lam = (l16 * 4 + lg) * 8;   // lane's ushort offset in a 1KB sub-tile

  const int Bid = blockIdx.x;
  const int b = Bid & 7;                     // batch (XCD affinity)
  const int i_ = (Bid >> 3) & 31;
  const int j_ = Bid >> 8;
  const int p = (j_ == 0) ? i_ : (j_ == 1) ? (127 - i_) : (j_ == 2) ? (32 + i_) : (95 - i_);
  const int qc0 = 2 * p, qc1 = 2 * p + 1;
  const int q0a = qc0 * 16, q0b = qc1 * 16;
  const int T_total = (q0b + 16 + 63) >> 6;  // tiles covering KV [0, q0b+16)
  const int t0 = (wid * T_total) >> 2;
  const int t1 = ((wid + 1) * T_total) >> 2;

  const unsigned short* pqb = PQ + (size_t)b * 256 * 1024;

  // Q fragments for both chunks (B-operand of S^T mfma)
  bf16x8 qa0 = *(const bf16x8*)(pqb + ((size_t)qc0 * 2 + 0) * 512 + lam);
  bf16x8 qa1 = *(const bf16x8*)(pqb + ((size_t)qc0 * 2 + 1) * 512 + lam);
  bf16x8 qb0 = *(const bf16x8*)(pqb + ((size_t)qc1 * 2 + 0) * 512 + lam);
  bf16x8 qb1 = *(const bf16x8*)(pqb + ((size_t)qc1 * 2 + 1) * 512 + lam);

  f32x4 oA[4], oB[4];
#pragma unroll
  for (int dd = 0; dd < 4; ++dd) { oA[dd] = (f32x4)0.0f; oB[dd] = (f32x4)0.0f; }
  float mA = -3.0e38f, lA = 0.0f, mB = -3.0e38f, lB = 0.0f;

  // running pointers (strength-reduced): K tile = 4096 ushorts, V tile = 4096
  const unsigned short* kp = PK + (size_t)b * 256 * 1024 + (size_t)t0 * 4096 + lam;
  const unsigned short* vp = PV + (size_t)b * 64 * 8 * 512 + (size_t)t0 * 4096 + lam;

  if (t0 < t1) {
    // preload K tile t0
    bf16x8 kf[8], kn[8];
#pragma unroll
    for (int t = 0; t < 4; ++t) {
      kf[2 * t] = *(const bf16x8*)(kp + t * 1024);
      kf[2 * t + 1] = *(const bf16x8*)(kp + t * 1024 + 512);
    }

    for (int it = t0; it < t1; ++it) {
      const int kv0 = it << 6;

      // prefetch next K tile (unconditional; last read lands in adjacent ws
      // region, never consumed)
#pragma unroll
      for (int t = 0; t < 4; ++t) {
        kn[2 * t] = *(const bf16x8*)(kp + 4096 + t * 1024);
        kn[2 * t + 1] = *(const bf16x8*)(kp + 4096 + t * 1024 + 512);
      }
      // V fragments for this tile (consumed at PV A / PV B)
      bf16x8 vf[8];
#pragma unroll
      for (int dd = 0; dd < 4; ++dd) {
        vf[2 * dd] = *(const bf16x8*)(vp + dd * 1024);
        vf[2 * dd + 1] = *(const bf16x8*)(vp + dd * 1024 + 512);
      }

      // QK^T for both chunks from kf
      f32x4 s0[4], s1[4];
      __builtin_amdgcn_s_setprio(1);
#pragma unroll
      for (int t = 0; t < 4; ++t) {
        f32x4 z = (f32x4)0.0f;
        z = __builtin_amdgcn_mfma_f32_16x16x32_bf16(kf[2 * t], qa0, z, 0, 0, 0);
        s0[t] = __builtin_amdgcn_mfma_f32_16x16x32_bf16(kf[2 * t + 1], qa1, z, 0, 0, 0);
        z = (f32x4)0.0f;
        z = __builtin_amdgcn_mfma_f32_16x16x32_bf16(kf[2 * t], qb0, z, 0, 0, 0);
        s1[t] = __builtin_amdgcn_mfma_f32_16x16x32_bf16(kf[2 * t + 1], qb1, z, 0, 0, 0);
      }
      __builtin_amdgcn_s_setprio(0);

      // ---- chunk A: mask, softmax (log2 domain), P->LDS, PV ----
      if (kv0 + 64 > q0a) {
        const int base = kv0 + lg * 4 - q0a - l16;
#pragma unroll
        for (int t = 0; t < 4; ++t)
#pragma unroll
          for (int r = 0; r < 4; ++r)
            if (base + 16 * t + r > 0) s0[t][r] = -3.0e38f;
      }
      {
        float mx = s0[0][0];
#pragma unroll
        for (int t = 0; t < 4; ++t)
#pragma unroll
          for (int r = 0; r < 4; ++r) mx = fmaxf(mx, s0[t][r]);
        mx = fmaxf(mx, __shfl_xor(mx, 16));
        mx = fmaxf(mx, __shfl_xor(mx, 32));
        if (!__all(mx <= mA)) {
          float mn = fmaxf(mA, mx);
          float al = FEXP2(mA - mn);
          mA = mn; lA *= al;
#pragma unroll
          for (int dd = 0; dd < 4; ++dd) oA[dd] *= al;
        }
        float ps = 0.0f;
#pragma unroll
        for (int t = 0; t < 4; ++t) {
          float p0 = FEXP2(s0[t][0] - mA);
          float p1 = FEXP2(s0[t][1] - mA);
          float p2 = FEXP2(s0[t][2] - mA);
          float p3 = FEXP2(s0[t][3] - mA);
          ps += (p0 + p1) + (p2 + p3);
          u32x2 w;
          w[0] = BFPACK(p0, p1);
          w[1] = BFPACK(p2, p3);
          *(u32x2*)&Pl[wid][0][l16][16 * t + lg * 4] = w;   // P^T[q=l16][kv]
        }
        ps += __shfl_xor(ps, 16);
        ps += __shfl_xor(ps, 32);
        lA += ps;
      }
      {
        bf16x8 pf0 = *(const bf16x8*)&Pl[wid][0][l16][lg * 8];
        bf16x8 pf1 = *(const bf16x8*)&Pl[wid][0][l16][32 + lg * 8];
        __builtin_amdgcn_s_setprio(1);
#pragma unroll
        for (int dd = 0; dd < 4; ++dd) {
          oA[dd] = __builtin_amdgcn_mfma_f32_16x16x32_bf16(vf[2 * dd], pf0, oA[dd], 0, 0, 0);
          oA[dd] = __builtin_amdgcn_mfma_f32_16x16x32_bf16(vf[2 * dd + 1], pf1, oA[dd], 0, 0, 0);
        }
        __builtin_amdgcn_s_setprio(0);
      }

      // ---- chunk B ----
      if (kv0 + 64 > q0b) {
        const int base = kv0 + lg * 4 - q0b - l16;
#pragma unroll
        for (int t = 0; t < 4; ++t)
#pragma unroll
          for (int r = 0; r < 4; ++r)
            if (base + 16 * t + r > 0) s1[t][r] = -3.0e38f;
      }
      {
        float mx = s1[0][0];
#pragma unroll
        for (int t = 0; t < 4; ++t)
#pragma unroll
          for (int r = 0; r < 4; ++r) mx = fmaxf(mx, s1[t][r]);
        mx = fmaxf(mx, __shfl_xor(mx, 16));
        mx = fmaxf(mx, __shfl_xor(mx, 32));
        if (!__all(mx <= mB)) {
          float mn = fmaxf(mB, mx);
          float al = FEXP2(mB - mn);
          mB = mn; lB *= al;
#pragma unroll
          for (int dd = 0; dd < 4; ++dd) oB[dd] *= al;
        }
        float ps = 0.0f;
#pragma unroll
        for (int t = 0; t < 4; ++t) {
          float p0 = FEXP2(s1[t][0] - mB);
          float p1 = FEXP2(s1[t][1] - mB);
          float p2 = FEXP2(s1[t][2] - mB);
          float p3 = FEXP2(s1[t][3] - mB);
          ps += (p0 + p1) + (p2 + p3);
          u32x2 w;
          w[0] = BFPACK(p0, p1);
          w[1] = BFPACK(p2, p3);
          *(u32x2*)&Pl[wid][1][l16][16 * t + lg * 4] = w;
        }
        ps += __shfl_xor(ps, 16);
        ps += __shfl_xor(ps, 32);
        lB += ps;
      }
      {
        bf16x8 pf0 = *(const bf16x8*)&Pl[wid][1][l16][lg * 8];
        bf16x8 pf1 = *(const bf16x8*)&Pl[wid][1][l16][32 + lg * 8];
        __builtin_amdgcn_s_setprio(1);
#pragma unroll
        for (int dd = 0; dd < 4; ++dd) {
          oB[dd] = __builtin_amdgcn_mfma_f32_16x16x32_bf16(vf[2 * dd], pf0, oB[dd], 0, 0, 0);
          oB[dd] = __builtin_amdgcn_mfma_f32_16x16x32_bf16(vf[2 * dd + 1], pf1, oB[dd], 0, 0, 0);
        }
        __builtin_amdgcn_s_setprio(0);
      }

#pragma unroll
      for (int j = 0; j < 8; ++j) kf[j] = kn[j];
      kp += 4096;
      vp += 4096;
    }
  }

  // ---- two-phase LSE merge (reuse LDS) ----
#define MERGE_PHASE(MV, LV, OV, Q0)                                            \
  {                                                                            \
    if (lg == 0) { Msm[wid][l16] = MV; Lsm[wid][l16] = LV; }                   \
    _Pragma("unroll") for (int dd = 0; dd < 4; ++dd)                           \
      _Pragma("unroll") for (int r = 0; r < 4; ++r)                            \
          Osm[wid][dd][lg * 4 + r][l16] = OV[dd][r];                           \
    __syncthreads();                                                           \
    if (wid == 0) {                                                            \
      float M = Msm[0][l16];                                                   \
      _Pragma("unroll") for (int w = 1; w < 4; ++w) M = fmaxf(M, Msm[w][l16]); \
      float L = 0.0f;                                                          \
      f32x4 oc[4];                                                             \
      _Pragma("unroll") for (int dd = 0; dd < 4; ++dd) oc[dd] = (f32x4)0.0f;   \
      _Pragma("unroll") for (int w = 0; w < 4; ++w) {                          \
        float sc = FEXP2(Msm[w][l16] - M);                                     \
        L += Lsm[w][l16] * sc;                                                 \
        _Pragma("unroll") for (int dd = 0; dd < 4; ++dd)                       \
          _Pragma("unroll") for (int r = 0; r < 4; ++r)                        \
              oc[dd][r] += Osm[w][dd][lg * 4 + r][l16] * sc;                   \
      }                                                                        \
      const float inv = 1.0f / L;                                              \
      float* op = out + ((size_t)b * SEQ + (Q0) + l16) * HEAD;                 \
      _Pragma("unroll") for (int dd = 0; dd < 4; ++dd)                         \
        _Pragma("unroll") for (int r = 0; r < 4; ++r)                          \
            op[16 * dd + lg * 4 + r] = oc[dd][r] * inv;                        \
    }                                                                          \
    __syncthreads();                                                           \
  }
  MERGE_PHASE(mA, lA, oA, q0a)
  MERGE_PHASE(mB, lB, oB, q0b)
#undef MERGE_PHASE
}

extern "C" void kernel_launch(void* const* d_in, const int* in_sizes, int n_in,
                              void* d_out, int out_size, void* d_ws, size_t ws_size,
                              hipStream_t stream) {
  (void)in_sizes; (void)n_in; (void)out_size; (void)ws_size;
  const float* x = (const float*)d_in[0];
  const float* W = (const float*)d_in[1];
  float* out = (float*)d_out;

  const size_t MB4 = (size_t)4 * 1024 * 1024;
  unsigned short* Wt = (unsigned short*)d_ws;                               // 384 KB
  unsigned short* PK = (unsigned short*)((char*)d_ws + 512 * 1024);         // 4 MB
  unsigned short* PQ = (unsigned short*)((char*)d_ws + 512 * 1024 + MB4);   // 4 MB
  unsigned short* PV = (unsigned short*)((char*)d_ws + 512 * 1024 + 2 * MB4); // 4 MB

  hipLaunchKernelGGL(wt_kernel, dim3((EMB * N3) / 256), dim3(256), 0, stream, W, Wt);
  hipLaunchKernelGGL(qkv_kernel, dim3((BATCH * SEQ) / BM), dim3(256), 0, stream, x, Wt, PK, PQ, PV);
  hipLaunchKernelGGL(attn_kernel, dim3(BATCH * 128), dim3(256), 0, stream, PK, PQ, PV, out);
}